// Round 6
// baseline (1575.990 us; speedup 1.0000x reference)
//
#include <hip/hip_runtime.h>
#include <hip/hip_bf16.h>
#include <math.h>

// SpaFormer forward. bf16-MFMA GEMMs + 1-wave-block MFMA attention.
// B=16 N=512 L=4 H=8 DK=DV=64 DM=512 DI=2048 M=64
//
// ws layout (bytes), total 93.9 MB:
//   f_x   f32  @ 0           16,777,216  (x stream, in-place LN)
//   qkvb  bf16 @ 16,777,216  25,165,824  ([8192][1536] fused q|k|v)
//   tb    bf16 @ 41,943,040   8,388,608  (fe1 out / attn out; h1b/h2b later)
//   midb  bf16 @ 16,777,216  33,554,432  (FFN mid; aliases qkvb+tb, dead then)
//   xb    bf16 @ 50,331,648   8,388,608  (bf16 x; ALSO reused as kP during attn:
//                                         xb dead after QKV GEMM, rewritten by ln1)
//   vT    bf16 @ 58,720,256   8,388,608  ([bh][64][512] transposed V)
//   wTall bf16 @ 67,108,864  26,738,688  (ALL transposed weights)
//   qkbias f32 @ 93,847,552      24,576

using bf16   = __bf16;
using bf16x4 = __attribute__((ext_vector_type(4))) __bf16;
using bf16x8 = __attribute__((ext_vector_type(8))) __bf16;
using f32x4  = __attribute__((ext_vector_type(4))) float;

__device__ __forceinline__ void mfma16(f32x4& d, bf16x8 a, bf16x8 b) {
    // D(16x16) = A(16x32)*B(32x16)+D. A/B: lane holds row/col (lane&15),
    // k = (lane>>4)*8+0..7. D: col=lane&15, row=(lane>>4)*4+reg.
    asm("v_mfma_f32_16x16x32_bf16 %0, %1, %2, %0" : "+v"(d) : "v"(a), "v"(b));
}

// ---------------- pack bq|bk|bv into [L][1536] ----------------
__global__ __launch_bounds__(256) void packb_kernel(
        const float* __restrict__ bq, const float* __restrict__ bk,
        const float* __restrict__ bv, float* __restrict__ out) {
    int i = blockIdx.x * 256 + threadIdx.x;
    if (i >= 6144) return;
    int l = i / 1536, c = i % 1536;
    out[i] = c < 512 ? bq[l * 512 + c] : c < 1024 ? bk[l * 512 + c - 512]
                                                  : bv[l * 512 + c - 1024];
}

// ---------------- ALL weight transposes, fp32 [K][N] -> bf16 [N][K] ----------------
__global__ __launch_bounds__(256) void transall_kernel(
        const float* __restrict__ fe_w2, const float* __restrict__ wq,
        const float* __restrict__ wk, const float* __restrict__ wv,
        const float* __restrict__ wo, const float* __restrict__ w1,
        const float* __restrict__ w2, const float* __restrict__ lin_w,
        const float* __restrict__ dec_w1, bf16* __restrict__ dst) {
    __shared__ float t[32][33];
    int id = blockIdx.x;
    const float* src; bf16* d; int K, N, ti;
    if (id < 256)        { src = fe_w2;  d = dst + 12582912; K = 512; N = 512; ti = id; }
    else if (id < 12544) {
        int u = id - 256, l = u / 3072, r = u % 3072;
        bf16* base = dst + (size_t)l * 3145728;
        if      (r < 256)  { src = wq + (size_t)l * 262144;  d = base;           K = 512;  N = 512;  ti = r; }
        else if (r < 512)  { src = wk + (size_t)l * 262144;  d = base + 262144;  K = 512;  N = 512;  ti = r - 256; }
        else if (r < 768)  { src = wv + (size_t)l * 262144;  d = base + 524288;  K = 512;  N = 512;  ti = r - 512; }
        else if (r < 1024) { src = wo + (size_t)l * 262144;  d = base + 786432;  K = 512;  N = 512;  ti = r - 768; }
        else if (r < 2048) { src = w1 + (size_t)l * 1048576; d = base + 1048576; K = 512;  N = 2048; ti = r - 1024; }
        else               { src = w2 + (size_t)l * 1048576; d = base + 2097152; K = 2048; N = 512;  ti = r - 2048; }
    }
    else if (id < 12800) { src = lin_w;  d = dst + 12845056; K = 512; N = 512; ti = id - 12544; }
    else                 { src = dec_w1; d = dst + 13107200; K = 512; N = 512; ti = id - 12800; }
    int nt = N >> 5;
    int n0 = (ti % nt) * 32, k0 = (ti / nt) * 32;
    int tx = threadIdx.x & 31, ty = threadIdx.x >> 5;
#pragma unroll
    for (int i = 0; i < 4; i++)
        t[ty + i * 8][tx] = src[(size_t)(k0 + ty + i * 8) * N + n0 + tx];
    __syncthreads();
#pragma unroll
    for (int i = 0; i < 4; i++)
        d[(size_t)(n0 + ty + i * 8) * K + k0 + tx] = (bf16)t[tx][ty + i * 8];
}

// ---------------- V transpose + K pack: vT[bh][64][512], kP[bh][512][64] ----------------
__global__ __launch_bounds__(256) void vt_kernel(
        const bf16* __restrict__ qkv, bf16* __restrict__ vT, bf16* __restrict__ kP) {
    __shared__ bf16 t[32][33];
    int s = blockIdx.z;                      // b*8+h
    int m0 = blockIdx.x * 32, d0 = blockIdx.y * 32;
    int tx = threadIdx.x & 31, ty = threadIdx.x >> 5;
    int b = s >> 3, h = s & 7;
    const bf16* srcv = qkv + 1024 + (size_t)h * 64;
    const bf16* srck = qkv + 512 + (size_t)h * 64;
#pragma unroll
    for (int i = 0; i < 4; i++) {
        int m = m0 + ty + i * 8;
        t[ty + i * 8][tx] = srcv[(size_t)(b * 512 + m) * 1536 + d0 + tx];
        kP[((size_t)s * 512 + m) * 64 + d0 + tx] =
            srck[(size_t)(b * 512 + m) * 1536 + d0 + tx];
    }
    __syncthreads();
#pragma unroll
    for (int i = 0; i < 4; i++)
        vT[((size_t)s * 64 + d0 + ty + i * 8) * 512 + m0 + tx] = t[tx][ty + i * 8];
}

// ---------------- feature-encoder first linear (K=3), bf16 out ----------------
__global__ __launch_bounds__(256) void fe1_kernel(
        const float* __restrict__ feat, const float* __restrict__ w1,
        const float* __restrict__ b1, bf16* __restrict__ out) {
    int idx = blockIdx.x * 256 + threadIdx.x;
    int r = idx >> 9, j = idx & 511;
    float f0 = feat[r * 3 + 0], f1 = feat[r * 3 + 1], f2 = feat[r * 3 + 2];
    out[(size_t)r * 512 + j] = (bf16)
        fmaf(f0, w1[j], fmaf(f1, w1[512 + j], fmaf(f2, w1[1024 + j], b1[j])));
}

// ---------------- bf16 MFMA GEMM (proven) ----------------
template<int EPI, bool WF32, bool WB16>
__global__ __launch_bounds__(256) void mm_kernel(
        const bf16* __restrict__ A, const bf16* __restrict__ Bt,
        const float* __restrict__ bias, const float* __restrict__ res,
        float* __restrict__ Cf, bf16* __restrict__ Cb,
        int M, int N, int K) {
    __shared__ bf16 Al[2][8192];
    __shared__ bf16 Bl[2][8192];
    const int tid = threadIdx.x;
    const int lane = tid & 63, wid = tid >> 6;
    const int r0 = blockIdx.y * 128, c0 = blockIdx.x * 128;
    const int wr = (wid >> 1) * 64, wc = (wid & 1) * 64;

    f32x4 acc[4][4] = {};
    const int kTiles = K >> 6;

#define STAGE(buf, kt)                                                                   \
    {                                                                                    \
        const bf16* ga = A + (size_t)r0 * K + (kt) * 64;                                 \
        const bf16* gb = Bt + (size_t)c0 * K + (kt) * 64;                                \
        _Pragma("unroll")                                                                \
        for (int i_ = 0; i_ < 4; i_++) {                                                 \
            int s = tid + i_ * 256;                                                      \
            int row = s >> 3;                                                            \
            int ssl = (s & 7) ^ (row & 7);                                               \
            __builtin_amdgcn_global_load_lds(                                            \
                (const __attribute__((address_space(1))) void*)(ga + (size_t)row * K + ssl * 8), \
                (__attribute__((address_space(3))) void*)(&Al[buf][s * 8]), 16, 0, 0);   \
            __builtin_amdgcn_global_load_lds(                                            \
                (const __attribute__((address_space(1))) void*)(gb + (size_t)row * K + ssl * 8), \
                (__attribute__((address_space(3))) void*)(&Bl[buf][s * 8]), 16, 0, 0);   \
        }                                                                                \
    }

    STAGE(0, 0);
    __syncthreads();

    for (int kt = 0; kt < kTiles; kt++) {
        if (kt + 1 < kTiles) STAGE((kt + 1) & 1, kt + 1);
        const bf16* al = Al[kt & 1];
        const bf16* bl = Bl[kt & 1];
#pragma unroll
        for (int kk = 0; kk < 2; kk++) {
            bf16x8 af[4], bfr[4];
#pragma unroll
            for (int i = 0; i < 4; i++) {
                int arow = wr + i * 16 + (lane & 15);
                int slot = kk * 4 + (lane >> 4);
                af[i] = *(const bf16x8*)(al + arow * 64 + ((slot ^ (arow & 7)) << 3));
                int brow = wc + i * 16 + (lane & 15);
                bfr[i] = *(const bf16x8*)(bl + brow * 64 + ((slot ^ (brow & 7)) << 3));
            }
#pragma unroll
            for (int i = 0; i < 4; i++)
#pragma unroll
                for (int j = 0; j < 4; j++)
                    mfma16(acc[i][j], af[i], bfr[j]);
        }
        __syncthreads();
    }
#undef STAGE

    asm volatile("s_nop 7\n\ts_nop 7");

#pragma unroll
    for (int i = 0; i < 4; i++)
#pragma unroll
        for (int j = 0; j < 4; j++)
#pragma unroll
            for (int q = 0; q < 4; q++) {
                int row = r0 + wr + i * 16 + ((lane >> 4) << 2) + q;
                int col = c0 + wc + j * 16 + (lane & 15);
                float v = acc[i][j][q] + bias[col];
                if (res) v += res[(size_t)row * N + col];
                if (EPI == 1) v = fmaxf(v, 0.f);
                if (EPI == 2) v = 0.5f * v * (1.f + erff(v * 0.7071067811865475f));
                if (WF32) Cf[(size_t)row * N + col] = v;
                if (WB16) Cb[(size_t)row * N + col] = (bf16)v;
            }
}

// ---------------- LayerNorm over 512 (in-place capable), f32 + bf16 out ----------------
__global__ __launch_bounds__(256) void ln_kernel(
        const float* __restrict__ in, float* __restrict__ outf, bf16* __restrict__ outb,
        const float* __restrict__ g, const float* __restrict__ b) {
    const int lane = threadIdx.x & 63;
    const size_t row = (size_t)blockIdx.x * 4 + (threadIdx.x >> 6);
    const float* x = in + row * 512;
    float4 a0 = *(const float4*)&x[lane * 4];
    float4 a1 = *(const float4*)&x[256 + lane * 4];
    float s = a0.x + a0.y + a0.z + a0.w + a1.x + a1.y + a1.z + a1.w;
#pragma unroll
    for (int off = 32; off >= 1; off >>= 1) s += __shfl_xor(s, off);
    float mean = s * (1.f / 512.f);
    float d, vs = 0.f;
    d = a0.x - mean; vs += d * d;  d = a0.y - mean; vs += d * d;
    d = a0.z - mean; vs += d * d;  d = a0.w - mean; vs += d * d;
    d = a1.x - mean; vs += d * d;  d = a1.y - mean; vs += d * d;
    d = a1.z - mean; vs += d * d;  d = a1.w - mean; vs += d * d;
#pragma unroll
    for (int off = 32; off >= 1; off >>= 1) vs += __shfl_xor(vs, off);
    float inv = rsqrtf(vs * (1.f / 512.f) + 1e-6f);
    float4 g0 = *(const float4*)&g[lane * 4];
    float4 g1 = *(const float4*)&g[256 + lane * 4];
    float4 b0 = *(const float4*)&b[lane * 4];
    float4 b1v = *(const float4*)&b[256 + lane * 4];
    float o[8];
    o[0] = (a0.x - mean) * inv * g0.x + b0.x;
    o[1] = (a0.y - mean) * inv * g0.y + b0.y;
    o[2] = (a0.z - mean) * inv * g0.z + b0.z;
    o[3] = (a0.w - mean) * inv * g0.w + b0.w;
    o[4] = (a1.x - mean) * inv * g1.x + b1v.x;
    o[5] = (a1.y - mean) * inv * g1.y + b1v.y;
    o[6] = (a1.z - mean) * inv * g1.z + b1v.z;
    o[7] = (a1.w - mean) * inv * g1.w + b1v.w;
    float* y = outf + row * 512;
    *(float4*)&y[lane * 4] = make_float4(o[0], o[1], o[2], o[3]);
    *(float4*)&y[256 + lane * 4] = make_float4(o[4], o[5], o[6], o[7]);
    bf16x4 p0, p1;
#pragma unroll
    for (int i = 0; i < 4; i++) { p0[i] = (bf16)o[i]; p1[i] = (bf16)o[4 + i]; }
    *(bf16x4*)&outb[row * 512 + lane * 4] = p0;
    *(bf16x4*)&outb[row * 512 + 256 + lane * 4] = p1;
}

// ---------------- MFMA attention, 1-wave blocks, grid (32 qtiles, 128 bh) ----------------
// 16 q-rows per block/wave. No barriers (wave-coherent LDS). K from packed kP.
__global__ __launch_bounds__(64, 4) void attn_kernel(
        const bf16* __restrict__ qb, const bf16* __restrict__ kP,
        const bf16* __restrict__ vT, const float* __restrict__ rpos,
        const float* __restrict__ wp, const float* __restrict__ bp,
        bf16* __restrict__ out) {
    __shared__ bf16 p_lds[16][128];      // XOR-swizzled P tile
    __shared__ float qw_lds[16][4];
    __shared__ bf16 o_lds[16][64];
    const int lane = threadIdx.x;
    const int bh = blockIdx.y, b = bh >> 3, h = bh & 7;
    const int n0 = blockIdx.x * 16;
    const int lo = lane & 15, hi = lane >> 4;
    const float scale = 0.125f;

    const bf16* qbase = qb + (size_t)(b * 512) * 1536 + h * 64;
    const bf16* kbase = kP + (size_t)bh * 32768;   // [512][64]
    const bf16* vbase = vT + (size_t)bh * 32768;   // [64][512]
    const float* rbase = rpos + (size_t)(b * 512 + n0) * 1536;

    // qw3 per row: lane -> (r = lane>>2, j = lane&3)
    {
        int r = lane >> 2, j = lane & 3;
        const float* wvec = (j < 3) ? wp + ((size_t)j * 8 + h) * 64 : bp + (size_t)h * 64;
        const bf16* qr = qbase + (size_t)(n0 + r) * 1536;
        float s = 0.f;
#pragma unroll
        for (int c8 = 0; c8 < 8; c8++) {
            bf16x8 v8 = *(const bf16x8*)(qr + c8 * 8);
#pragma unroll
            for (int i = 0; i < 8; i++) s = fmaf((float)v8[i], wvec[c8 * 8 + i], s);
        }
        qw_lds[r][j] = s;
    }
    bf16x8 af0 = *(const bf16x8*)(qbase + (size_t)(n0 + lo) * 1536 + hi * 8);
    bf16x8 af1 = *(const bf16x8*)(qbase + (size_t)(n0 + lo) * 1536 + 32 + hi * 8);
    float qw[4][4];
#pragma unroll
    for (int q = 0; q < 4; q++)
#pragma unroll
        for (int j = 0; j < 4; j++) qw[q][j] = qw_lds[hi * 4 + q][j];

    f32x4 oacc[4] = {};
    float mrun[4] = {-1e30f, -1e30f, -1e30f, -1e30f};
    float lrun[4] = {0.f, 0.f, 0.f, 0.f};

    for (int mc = 0; mc < 4; mc++) {
        const int m0 = mc * 128;
        // ---- QK^T: 8 m-tiles of 16, B-frags from packed kP (128B rows) ----
        f32x4 st[8];
#pragma unroll
        for (int t = 0; t < 8; t++) {
            const bf16* kr = kbase + (size_t)(m0 + t * 16 + lo) * 64 + hi * 8;
            bf16x8 kf0 = *(const bf16x8*)kr;
            bf16x8 kf1 = *(const bf16x8*)(kr + 32);
            f32x4 z = {};
            mfma16(z, af0, kf0);
            mfma16(z, af1, kf1);
            st[t] = z;
        }
        asm volatile("s_nop 7\n\ts_nop 7");   // MFMA->VALU hazard
        // ---- rel-pos: st += qw . rpos ----
#pragma unroll
        for (int t = 0; t < 8; t++) {
#pragma unroll
            for (int q = 0; q < 4; q++) {
                const float* rp = rbase + ((size_t)(hi * 4 + q) * 512 + m0 + t * 16 + lo) * 3;
                st[t][q] += fmaf(qw[q][0], rp[0],
                             fmaf(qw[q][1], rp[1], fmaf(qw[q][2], rp[2], qw[q][3])));
            }
        }
        // ---- online softmax (rows = hi*4+q, cross-lane over lo nibble) ----
        float fac[4];
#pragma unroll
        for (int q = 0; q < 4; q++) {
            float mx = st[0][q];
#pragma unroll
            for (int t = 1; t < 8; t++) mx = fmaxf(mx, st[t][q]);
            mx = fmaxf(mx, __shfl_xor(mx, 1));
            mx = fmaxf(mx, __shfl_xor(mx, 2));
            mx = fmaxf(mx, __shfl_xor(mx, 4));
            mx = fmaxf(mx, __shfl_xor(mx, 8));
            float mnew = fmaxf(mrun[q], mx);
            fac[q] = __expf((mrun[q] - mnew) * scale);
            float ls = 0.f;
#pragma unroll
            for (int t = 0; t < 8; t++) {
                float e = __expf((st[t][q] - mnew) * scale);
                st[t][q] = e;
                ls += e;
            }
            ls += __shfl_xor(ls, 1);
            ls += __shfl_xor(ls, 2);
            ls += __shfl_xor(ls, 4);
            ls += __shfl_xor(ls, 8);
            lrun[q] = lrun[q] * fac[q] + ls;
            mrun[q] = mnew;
        }
#pragma unroll
        for (int dt = 0; dt < 4; dt++) {
            oacc[dt][0] *= fac[0]; oacc[dt][1] *= fac[1];
            oacc[dt][2] *= fac[2]; oacc[dt][3] *= fac[3];
        }
        // ---- P -> LDS (bf16), 8-elem-chunk XOR swizzle, D-layout -> A-layout ----
#pragma unroll
        for (int t = 0; t < 8; t++) {
#pragma unroll
            for (int q = 0; q < 4; q++) {
                int rl = hi * 4 + q;
                int c = t * 16 + lo;
                int cs = (((c >> 3) ^ (rl & 7)) << 3) | (c & 7);
                p_lds[rl][cs] = (bf16)st[t][q];
            }
        }
        // ---- PV: A = P from LDS, B = vT rows (contiguous) ----
#pragma unroll
        for (int ks = 0; ks < 4; ks++) {
            int chunk = (ks * 4 + hi) ^ (lo & 7);
            bf16x8 pa = *(const bf16x8*)&p_lds[lo][chunk << 3];
#pragma unroll
            for (int dt = 0; dt < 4; dt++) {
                bf16x8 vf = *(const bf16x8*)(vbase + (size_t)(dt * 16 + lo) * 512 + m0 + ks * 32 + hi * 8);
                mfma16(oacc[dt], pa, vf);
            }
        }
    }
    asm volatile("s_nop 7\n\ts_nop 7");
    // ---- epilogue: normalize, bounce through LDS, coalesced bf16 write ----
    float inv[4];
#pragma unroll
    for (int q = 0; q < 4; q++) inv[q] = 1.f / lrun[q];
#pragma unroll
    for (int dt = 0; dt < 4; dt++)
#pragma unroll
        for (int q = 0; q < 4; q++)
            o_lds[hi * 4 + q][dt * 16 + lo] = (bf16)(oacc[dt][q] * inv[q]);
    {
        int r = lane >> 2, c = (lane & 3) * 16;
        bf16x8 w0 = *(const bf16x8*)&o_lds[r][c];
        bf16x8 w1 = *(const bf16x8*)&o_lds[r][c + 8];
        bf16* op = out + (size_t)(b * 512 + n0 + r) * 512 + h * 64 + c;
        *(bf16x8*)op = w0;
        *(bf16x8*)(op + 8) = w1;
    }
}

// ---------------- gather masked positions (f32 out + bf16 copy) ----------------
__global__ __launch_bounds__(256) void gather_kernel(
        const float* __restrict__ x, const int* __restrict__ mp,
        float* __restrict__ h1, bf16* __restrict__ h1b) {
    int idx = blockIdx.x * 256 + threadIdx.x;
    int row = idx >> 7, c4 = (idx & 127) * 4;
    int b = row >> 6;
    int src = mp[row];
    float4 v = *(const float4*)&x[((size_t)(b * 512 + src)) * 512 + c4];
    *(float4*)&h1[(size_t)row * 512 + c4] = v;
    bf16x4 p;
    p[0] = (bf16)v.x; p[1] = (bf16)v.y; p[2] = (bf16)v.z; p[3] = (bf16)v.w;
    *(bf16x4*)&h1b[(size_t)row * 512 + c4] = p;
}

// ---------------- final decoder dot (512 -> 1) ----------------
__global__ __launch_bounds__(256) void dec2_kernel(
        const float* __restrict__ dmid, const float* __restrict__ w2,
        const float* __restrict__ b2, float* __restrict__ out) {
    const int lane = threadIdx.x & 63;
    const int row = blockIdx.x * 4 + (threadIdx.x >> 6);
    float s = 0.f;
#pragma unroll
    for (int t = 0; t < 8; t++) {
        int c = lane + t * 64;
        s = fmaf(dmid[(size_t)row * 512 + c], w2[c], s);
    }
#pragma unroll
    for (int off = 32; off >= 1; off >>= 1) s += __shfl_xor(s, off);
    if (lane == 0) out[row] = s + b2[0];
}

extern "C" void kernel_launch(void* const* d_in, const int* in_sizes, int n_in,
                              void* d_out, int out_size, void* d_ws, size_t ws_size,
                              hipStream_t stream) {
    const float* feat   = (const float*)d_in[0];
    const float* rpos   = (const float*)d_in[1];
    const int*   mpos   = (const int*)d_in[2];
    const float* fe_w1  = (const float*)d_in[3];
    const float* fe_b1  = (const float*)d_in[4];
    const float* fe_w2  = (const float*)d_in[5];
    const float* fe_b2  = (const float*)d_in[6];
    const float* wq     = (const float*)d_in[7];
    const float* bq     = (const float*)d_in[8];
    const float* wk     = (const float*)d_in[9];
    const float* bk     = (const float*)d_in[10];
    const float* wv     = (const float*)d_in[11];
    const float* bv     = (const float*)d_in[12];
    const float* wp     = (const float*)d_in[13];
    const float* bp     = (const float*)d_in[14];
    const float* wo     = (const float*)d_in[15];
    const float* bo     = (const float*)d_in[16];
    const float* ln1_g  = (const float*)d_in[17];
    const float* ln1_b  = (const float*)d_in[18];
    const float* ffn_w1 = (const float*)d_in[19];
    const float* ffn_b1 = (const float*)d_in[20];
    const float* ffn_w2 = (const float*)d_in[21];
    const float* ffn_b2 = (const float*)d_in[22];
    const float* ln2_g  = (const float*)d_in[23];
    const float* ln2_b  = (const float*)d_in[24];
    const float* ln_g   = (const float*)d_in[25];
    const float* ln_b   = (const float*)d_in[26];
    const float* lin_w  = (const float*)d_in[27];
    const float* lin_b  = (const float*)d_in[28];
    const float* dec_w1 = (const float*)d_in[29];
    const float* dec_b1 = (const float*)d_in[30];
    const float* dec_w2 = (const float*)d_in[31];
    const float* dec_b2 = (const float*)d_in[32];

    char* W = (char*)d_ws;
    float* f_x    = (float*)(W);
    bf16*  qkvb   = (bf16*)(W + 16777216);
    bf16*  tb     = (bf16*)(W + 41943040);
    bf16*  midb   = (bf16*)(W + 16777216);   // aliases qkvb+tb (dead during FFN)
    bf16*  xb     = (bf16*)(W + 50331648);
    bf16*  kPb    = (bf16*)(W + 50331648);   // reuses xb region (xb dead post-QKV)
    bf16*  vTb    = (bf16*)(W + 58720256);
    bf16*  wTall  = (bf16*)(W + 67108864);
    float* qkbias = (float*)(W + 93847552);
    bf16*  h1b    = tb;
    bf16*  h2b    = tb + 524288;

    bf16* feT  = wTall + 12582912;
    bf16* linT = wTall + 12845056;
    bf16* decT = wTall + 13107200;

    float* outp  = (float*)d_out;
    float* o_dec = outp;                      // (16,64,1)
    float* o_h1  = outp + 1024;               // (16,64,512)
    float* o_h2  = outp + 1024 + 524288;      // (16,64,512)

    dim3 g512(4, 64), gQKV(12, 64), gF1(16, 64), gsm(4, 8);

    packb_kernel<<<24, 256, 0, stream>>>(bq, bk, bv, qkbias);
    transall_kernel<<<13056, 256, 0, stream>>>(fe_w2, wq, wk, wv, wo, ffn_w1, ffn_w2,
                                               lin_w, dec_w1, wTall);

    // feature encoder + shared LN
    fe1_kernel<<<16384, 256, 0, stream>>>(feat, fe_w1, fe_b1, tb);
    mm_kernel<0, true, false><<<g512, 256, 0, stream>>>(tb, feT, fe_b2, nullptr, f_x, nullptr, 8192, 512, 512);
    ln_kernel<<<2048, 256, 0, stream>>>(f_x, f_x, xb, ln_g, ln_b);

    for (int l = 0; l < 4; l++) {
        bf16* qT  = wTall + (size_t)l * 3145728;
        bf16* oT  = qT + 786432;
        bf16* w1T = qT + 1048576;
        bf16* w2T = qT + 2097152;

        mm_kernel<0, false, true><<<gQKV, 256, 0, stream>>>(xb, qT, qkbias + l * 1536, nullptr, nullptr, qkvb, 8192, 1536, 512);
        vt_kernel<<<dim3(16, 2, 128), 256, 0, stream>>>(qkvb, vTb, kPb);   // clobbers xb
        attn_kernel<<<dim3(32, 128), 64, 0, stream>>>(qkvb, kPb, vTb, rpos,
                                                      wp + (size_t)l * 1536, bp + (size_t)l * 512, tb);
        mm_kernel<0, true, false><<<g512, 256, 0, stream>>>(tb, oT, bo + l * 512, f_x, f_x, nullptr, 8192, 512, 512);
        ln_kernel<<<2048, 256, 0, stream>>>(f_x, f_x, xb, ln1_g + l * 512, ln1_b + l * 512);
        mm_kernel<1, false, true><<<gF1, 256, 0, stream>>>(xb, w1T, ffn_b1 + l * 2048, nullptr, nullptr, midb, 8192, 2048, 512);
        mm_kernel<0, true, false><<<g512, 256, 0, stream>>>(midb, w2T, ffn_b2 + l * 512, f_x, f_x, nullptr, 8192, 512, 2048);
        ln_kernel<<<2048, 256, 0, stream>>>(f_x, f_x, xb, ln2_g + l * 512, ln2_b + l * 512);
    }

    // masked gather + heads
    gather_kernel<<<512, 256, 0, stream>>>(f_x, mpos, o_h1, h1b);
    mm_kernel<2, true, false><<<gsm, 256, 0, stream>>>(h1b, linT, lin_b, nullptr, f_x, nullptr, 1024, 512, 512);
    ln_kernel<<<256, 256, 0, stream>>>(f_x, o_h2, h2b, ln_g, ln_b);
    mm_kernel<0, true, false><<<gsm, 256, 0, stream>>>(h2b, decT, dec_b1, nullptr, f_x, nullptr, 1024, 512, 512);
    dec2_kernel<<<256, 256, 0, stream>>>(f_x, dec_w2, dec_b2, o_dec);
}

// Round 7
// 1566.191 us; speedup vs baseline: 1.0063x; 1.0063x over previous
//
#include <hip/hip_runtime.h>
#include <hip/hip_bf16.h>
#include <math.h>

// SpaFormer forward. bf16-MFMA GEMMs + head-shared-rpos MFMA attention.
// B=16 N=512 L=4 H=8 DK=DV=64 DM=512 DI=2048 M=64
//
// ws layout (bytes), total 93.9 MB:
//   f_x   f32  @ 0           16,777,216  (x stream, in-place LN)
//   qkvb  bf16 @ 16,777,216  25,165,824  ([8192][1536] fused q|k|v)
//   tb    bf16 @ 41,943,040   8,388,608  (fe1 out / attn out; h1b/h2b later)
//   midb  bf16 @ 16,777,216  33,554,432  (FFN mid; aliases qkvb+tb, dead then)
//   xb    bf16 @ 50,331,648   8,388,608  (bf16 x; reused as kP during attn)
//   vT    bf16 @ 58,720,256   8,388,608  ([bh][64][512] transposed V)
//   wTall bf16 @ 67,108,864  26,738,688  (ALL transposed weights)
//   qkbias f32 @ 93,847,552      24,576

using bf16   = __bf16;
using bf16x4 = __attribute__((ext_vector_type(4))) __bf16;
using bf16x8 = __attribute__((ext_vector_type(8))) __bf16;
using f32x4  = __attribute__((ext_vector_type(4))) float;

__device__ __forceinline__ void mfma16(f32x4& d, bf16x8 a, bf16x8 b) {
    // D(16x16) = A(16x32)*B(32x16)+D. A/B: lane holds row/col (lane&15),
    // k = (lane>>4)*8+0..7. D: col=lane&15, row=(lane>>4)*4+reg.
    asm("v_mfma_f32_16x16x32_bf16 %0, %1, %2, %0" : "+v"(d) : "v"(a), "v"(b));
}

// ---------------- pack bq|bk|bv into [L][1536] ----------------
__global__ __launch_bounds__(256) void packb_kernel(
        const float* __restrict__ bq, const float* __restrict__ bk,
        const float* __restrict__ bv, float* __restrict__ out) {
    int i = blockIdx.x * 256 + threadIdx.x;
    if (i >= 6144) return;
    int l = i / 1536, c = i % 1536;
    out[i] = c < 512 ? bq[l * 512 + c] : c < 1024 ? bk[l * 512 + c - 512]
                                                  : bv[l * 512 + c - 1024];
}

// ---------------- ALL weight transposes, fp32 [K][N] -> bf16 [N][K] ----------------
__global__ __launch_bounds__(256) void transall_kernel(
        const float* __restrict__ fe_w2, const float* __restrict__ wq,
        const float* __restrict__ wk, const float* __restrict__ wv,
        const float* __restrict__ wo, const float* __restrict__ w1,
        const float* __restrict__ w2, const float* __restrict__ lin_w,
        const float* __restrict__ dec_w1, bf16* __restrict__ dst) {
    __shared__ float t[32][33];
    int id = blockIdx.x;
    const float* src; bf16* d; int K, N, ti;
    if (id < 256)        { src = fe_w2;  d = dst + 12582912; K = 512; N = 512; ti = id; }
    else if (id < 12544) {
        int u = id - 256, l = u / 3072, r = u % 3072;
        bf16* base = dst + (size_t)l * 3145728;
        if      (r < 256)  { src = wq + (size_t)l * 262144;  d = base;           K = 512;  N = 512;  ti = r; }
        else if (r < 512)  { src = wk + (size_t)l * 262144;  d = base + 262144;  K = 512;  N = 512;  ti = r - 256; }
        else if (r < 768)  { src = wv + (size_t)l * 262144;  d = base + 524288;  K = 512;  N = 512;  ti = r - 512; }
        else if (r < 1024) { src = wo + (size_t)l * 262144;  d = base + 786432;  K = 512;  N = 512;  ti = r - 768; }
        else if (r < 2048) { src = w1 + (size_t)l * 1048576; d = base + 1048576; K = 512;  N = 2048; ti = r - 1024; }
        else               { src = w2 + (size_t)l * 1048576; d = base + 2097152; K = 2048; N = 512;  ti = r - 2048; }
    }
    else if (id < 12800) { src = lin_w;  d = dst + 12845056; K = 512; N = 512; ti = id - 12544; }
    else                 { src = dec_w1; d = dst + 13107200; K = 512; N = 512; ti = id - 12800; }
    int nt = N >> 5;
    int n0 = (ti % nt) * 32, k0 = (ti / nt) * 32;
    int tx = threadIdx.x & 31, ty = threadIdx.x >> 5;
#pragma unroll
    for (int i = 0; i < 4; i++)
        t[ty + i * 8][tx] = src[(size_t)(k0 + ty + i * 8) * N + n0 + tx];
    __syncthreads();
#pragma unroll
    for (int i = 0; i < 4; i++)
        d[(size_t)(n0 + ty + i * 8) * K + k0 + tx] = (bf16)t[tx][ty + i * 8];
}

// ---------------- V transpose + K pack: vT[bh][64][512], kP[bh][512][64] ----------------
__global__ __launch_bounds__(256) void vt_kernel(
        const bf16* __restrict__ qkv, bf16* __restrict__ vT, bf16* __restrict__ kP) {
    __shared__ bf16 t[32][33];
    int s = blockIdx.z;                      // b*8+h
    int m0 = blockIdx.x * 32, d0 = blockIdx.y * 32;
    int tx = threadIdx.x & 31, ty = threadIdx.x >> 5;
    int b = s >> 3, h = s & 7;
    const bf16* srcv = qkv + 1024 + (size_t)h * 64;
    const bf16* srck = qkv + 512 + (size_t)h * 64;
#pragma unroll
    for (int i = 0; i < 4; i++) {
        int m = m0 + ty + i * 8;
        t[ty + i * 8][tx] = srcv[(size_t)(b * 512 + m) * 1536 + d0 + tx];
        kP[((size_t)s * 512 + m) * 64 + d0 + tx] =
            srck[(size_t)(b * 512 + m) * 1536 + d0 + tx];
    }
    __syncthreads();
#pragma unroll
    for (int i = 0; i < 4; i++)
        vT[((size_t)s * 64 + d0 + ty + i * 8) * 512 + m0 + tx] = t[tx][ty + i * 8];
}

// ---------------- feature-encoder first linear (K=3), bf16 out ----------------
__global__ __launch_bounds__(256) void fe1_kernel(
        const float* __restrict__ feat, const float* __restrict__ w1,
        const float* __restrict__ b1, bf16* __restrict__ out) {
    int idx = blockIdx.x * 256 + threadIdx.x;
    int r = idx >> 9, j = idx & 511;
    float f0 = feat[r * 3 + 0], f1 = feat[r * 3 + 1], f2 = feat[r * 3 + 2];
    out[(size_t)r * 512 + j] = (bf16)
        fmaf(f0, w1[j], fmaf(f1, w1[512 + j], fmaf(f2, w1[1024 + j], b1[j])));
}

// ---------------- bf16 MFMA GEMM (proven) ----------------
template<int EPI, bool WF32, bool WB16>
__global__ __launch_bounds__(256) void mm_kernel(
        const bf16* __restrict__ A, const bf16* __restrict__ Bt,
        const float* __restrict__ bias, const float* __restrict__ res,
        float* __restrict__ Cf, bf16* __restrict__ Cb,
        int M, int N, int K) {
    __shared__ bf16 Al[2][8192];
    __shared__ bf16 Bl[2][8192];
    const int tid = threadIdx.x;
    const int lane = tid & 63, wid = tid >> 6;
    const int r0 = blockIdx.y * 128, c0 = blockIdx.x * 128;
    const int wr = (wid >> 1) * 64, wc = (wid & 1) * 64;

    f32x4 acc[4][4] = {};
    const int kTiles = K >> 6;

#define STAGE(buf, kt)                                                                   \
    {                                                                                    \
        const bf16* ga = A + (size_t)r0 * K + (kt) * 64;                                 \
        const bf16* gb = Bt + (size_t)c0 * K + (kt) * 64;                                \
        _Pragma("unroll")                                                                \
        for (int i_ = 0; i_ < 4; i_++) {                                                 \
            int s = tid + i_ * 256;                                                      \
            int row = s >> 3;                                                            \
            int ssl = (s & 7) ^ (row & 7);                                               \
            __builtin_amdgcn_global_load_lds(                                            \
                (const __attribute__((address_space(1))) void*)(ga + (size_t)row * K + ssl * 8), \
                (__attribute__((address_space(3))) void*)(&Al[buf][s * 8]), 16, 0, 0);   \
            __builtin_amdgcn_global_load_lds(                                            \
                (const __attribute__((address_space(1))) void*)(gb + (size_t)row * K + ssl * 8), \
                (__attribute__((address_space(3))) void*)(&Bl[buf][s * 8]), 16, 0, 0);   \
        }                                                                                \
    }

    STAGE(0, 0);
    __syncthreads();

    for (int kt = 0; kt < kTiles; kt++) {
        if (kt + 1 < kTiles) STAGE((kt + 1) & 1, kt + 1);
        const bf16* al = Al[kt & 1];
        const bf16* bl = Bl[kt & 1];
#pragma unroll
        for (int kk = 0; kk < 2; kk++) {
            bf16x8 af[4], bfr[4];
#pragma unroll
            for (int i = 0; i < 4; i++) {
                int arow = wr + i * 16 + (lane & 15);
                int slot = kk * 4 + (lane >> 4);
                af[i] = *(const bf16x8*)(al + arow * 64 + ((slot ^ (arow & 7)) << 3));
                int brow = wc + i * 16 + (lane & 15);
                bfr[i] = *(const bf16x8*)(bl + brow * 64 + ((slot ^ (brow & 7)) << 3));
            }
#pragma unroll
            for (int i = 0; i < 4; i++)
#pragma unroll
                for (int j = 0; j < 4; j++)
                    mfma16(acc[i][j], af[i], bfr[j]);
        }
        __syncthreads();
    }
#undef STAGE

    asm volatile("s_nop 7\n\ts_nop 7");

#pragma unroll
    for (int i = 0; i < 4; i++)
#pragma unroll
        for (int j = 0; j < 4; j++)
#pragma unroll
            for (int q = 0; q < 4; q++) {
                int row = r0 + wr + i * 16 + ((lane >> 4) << 2) + q;
                int col = c0 + wc + j * 16 + (lane & 15);
                float v = acc[i][j][q] + bias[col];
                if (res) v += res[(size_t)row * N + col];
                if (EPI == 1) v = fmaxf(v, 0.f);
                if (EPI == 2) v = 0.5f * v * (1.f + erff(v * 0.7071067811865475f));
                if (WF32) Cf[(size_t)row * N + col] = v;
                if (WB16) Cb[(size_t)row * N + col] = (bf16)v;
            }
}

// ---------------- LayerNorm over 512 (in-place capable), f32 + bf16 out ----------------
__global__ __launch_bounds__(256) void ln_kernel(
        const float* __restrict__ in, float* __restrict__ outf, bf16* __restrict__ outb,
        const float* __restrict__ g, const float* __restrict__ b) {
    const int lane = threadIdx.x & 63;
    const size_t row = (size_t)blockIdx.x * 4 + (threadIdx.x >> 6);
    const float* x = in + row * 512;
    float4 a0 = *(const float4*)&x[lane * 4];
    float4 a1 = *(const float4*)&x[256 + lane * 4];
    float s = a0.x + a0.y + a0.z + a0.w + a1.x + a1.y + a1.z + a1.w;
#pragma unroll
    for (int off = 32; off >= 1; off >>= 1) s += __shfl_xor(s, off);
    float mean = s * (1.f / 512.f);
    float d, vs = 0.f;
    d = a0.x - mean; vs += d * d;  d = a0.y - mean; vs += d * d;
    d = a0.z - mean; vs += d * d;  d = a0.w - mean; vs += d * d;
    d = a1.x - mean; vs += d * d;  d = a1.y - mean; vs += d * d;
    d = a1.z - mean; vs += d * d;  d = a1.w - mean; vs += d * d;
#pragma unroll
    for (int off = 32; off >= 1; off >>= 1) vs += __shfl_xor(vs, off);
    float inv = rsqrtf(vs * (1.f / 512.f) + 1e-6f);
    float4 g0 = *(const float4*)&g[lane * 4];
    float4 g1 = *(const float4*)&g[256 + lane * 4];
    float4 b0 = *(const float4*)&b[lane * 4];
    float4 b1v = *(const float4*)&b[256 + lane * 4];
    float o[8];
    o[0] = (a0.x - mean) * inv * g0.x + b0.x;
    o[1] = (a0.y - mean) * inv * g0.y + b0.y;
    o[2] = (a0.z - mean) * inv * g0.z + b0.z;
    o[3] = (a0.w - mean) * inv * g0.w + b0.w;
    o[4] = (a1.x - mean) * inv * g1.x + b1v.x;
    o[5] = (a1.y - mean) * inv * g1.y + b1v.y;
    o[6] = (a1.z - mean) * inv * g1.z + b1v.z;
    o[7] = (a1.w - mean) * inv * g1.w + b1v.w;
    float* y = outf + row * 512;
    *(float4*)&y[lane * 4] = make_float4(o[0], o[1], o[2], o[3]);
    *(float4*)&y[256 + lane * 4] = make_float4(o[4], o[5], o[6], o[7]);
    bf16x4 p0, p1;
#pragma unroll
    for (int i = 0; i < 4; i++) { p0[i] = (bf16)o[i]; p1[i] = (bf16)o[4 + i]; }
    *(bf16x4*)&outb[row * 512 + lane * 4] = p0;
    *(bf16x4*)&outb[row * 512 + 256 + lane * 4] = p1;
}

// ---------------- MFMA attention, head-shared rpos ----------------
// grid (32 qtiles, 16 b), 512 threads = 8 waves, wave = head. Per 128-m chunk:
// block stages rpos[16][128][3] into padded LDS planes once; all 8 heads reuse.
__global__ __launch_bounds__(512, 4) void attn_kernel(
        const bf16* __restrict__ qb, const bf16* __restrict__ kP,
        const bf16* __restrict__ vT, const float* __restrict__ rpos,
        const float* __restrict__ wp, const float* __restrict__ bp,
        bf16* __restrict__ out) {
    __shared__ float rp_lds[3][16][132];   // padded pitch 132: r-stride not bank-aligned
    __shared__ float qw_lds[8][16][4];
    __shared__ bf16 p_lds[8][16][128];     // XOR-swizzled P tile per wave
    __shared__ bf16 o_lds[8][16][64];
    const int tid = threadIdx.x, lane = tid & 63, wid = tid >> 6;
    const int b = blockIdx.y, h = wid;
    const int n0 = blockIdx.x * 16;
    const int lo = lane & 15, hi = lane >> 4;
    const float scale = 0.125f;

    const bf16* qbase = qb + (size_t)(b * 512) * 1536 + h * 64;
    const bf16* kbase = kP + ((size_t)(b * 8 + h)) * 32768;   // [512][64]
    const bf16* vbase = vT + ((size_t)(b * 8 + h)) * 32768;   // [64][512]
    const float* rbase = rpos + (size_t)(b * 512 + n0) * 1536;

    // qw3 per row (per wave/head): lane -> (r = lane>>2, j = lane&3)
    {
        int r = lane >> 2, j = lane & 3;
        const float* wvec = (j < 3) ? wp + ((size_t)j * 8 + h) * 64 : bp + (size_t)h * 64;
        const bf16* qr = qbase + (size_t)(n0 + r) * 1536;
        float s = 0.f;
#pragma unroll
        for (int c8 = 0; c8 < 8; c8++) {
            bf16x8 v8 = *(const bf16x8*)(qr + c8 * 8);
#pragma unroll
            for (int i = 0; i < 8; i++) s = fmaf((float)v8[i], wvec[c8 * 8 + i], s);
        }
        qw_lds[wid][r][j] = s;
    }
    bf16x8 af0 = *(const bf16x8*)(qbase + (size_t)(n0 + lo) * 1536 + hi * 8);
    bf16x8 af1 = *(const bf16x8*)(qbase + (size_t)(n0 + lo) * 1536 + 32 + hi * 8);
    float qw[4][4];
#pragma unroll
    for (int q = 0; q < 4; q++)
#pragma unroll
        for (int j = 0; j < 4; j++) qw[q][j] = qw_lds[wid][hi * 4 + q][j];

    f32x4 oacc[4] = {};
    float mrun[4] = {-1e30f, -1e30f, -1e30f, -1e30f};
    float lrun[4] = {0.f, 0.f, 0.f, 0.f};

    for (int mc = 0; mc < 4; mc++) {
        const int m0 = mc * 128;
        // ---- stage rpos chunk: [16 rows][128 m][3] -> planes [p][r][m] ----
        __syncthreads();   // prior chunk's rel reads done before overwrite
#pragma unroll
        for (int k = 0; k < 12; k++) {
            int flat = tid + k * 512;            // 0..6143
            int r = flat / 384, rem = flat % 384;
            float v = rbase[(size_t)r * 1536 + m0 * 3 + rem];
            rp_lds[rem % 3][r][rem / 3] = v;
        }
        __syncthreads();
        // ---- QK^T: 8 m-tiles of 16, B-frags from packed kP (128B rows) ----
        f32x4 st[8];
#pragma unroll
        for (int t = 0; t < 8; t++) {
            const bf16* kr = kbase + (size_t)(m0 + t * 16 + lo) * 64 + hi * 8;
            bf16x8 kf0 = *(const bf16x8*)kr;
            bf16x8 kf1 = *(const bf16x8*)(kr + 32);
            f32x4 z = {};
            mfma16(z, af0, kf0);
            mfma16(z, af1, kf1);
            st[t] = z;
        }
        asm volatile("s_nop 7\n\ts_nop 7");   // MFMA->VALU hazard
        // ---- rel from LDS: st += qw . rp ----
#pragma unroll
        for (int t = 0; t < 8; t++) {
#pragma unroll
            for (int q = 0; q < 4; q++) {
                int r = hi * 4 + q, m = t * 16 + lo;
                st[t][q] += fmaf(qw[q][0], rp_lds[0][r][m],
                             fmaf(qw[q][1], rp_lds[1][r][m],
                              fmaf(qw[q][2], rp_lds[2][r][m], qw[q][3])));
            }
        }
        // ---- online softmax (rows = hi*4+q, cross-lane over lo nibble) ----
        float fac[4];
#pragma unroll
        for (int q = 0; q < 4; q++) {
            float mx = st[0][q];
#pragma unroll
            for (int t = 1; t < 8; t++) mx = fmaxf(mx, st[t][q]);
            mx = fmaxf(mx, __shfl_xor(mx, 1));
            mx = fmaxf(mx, __shfl_xor(mx, 2));
            mx = fmaxf(mx, __shfl_xor(mx, 4));
            mx = fmaxf(mx, __shfl_xor(mx, 8));
            float mnew = fmaxf(mrun[q], mx);
            fac[q] = __expf((mrun[q] - mnew) * scale);
            float ls = 0.f;
#pragma unroll
            for (int t = 0; t < 8; t++) {
                float e = __expf((st[t][q] - mnew) * scale);
                st[t][q] = e;
                ls += e;
            }
            ls += __shfl_xor(ls, 1);
            ls += __shfl_xor(ls, 2);
            ls += __shfl_xor(ls, 4);
            ls += __shfl_xor(ls, 8);
            lrun[q] = lrun[q] * fac[q] + ls;
            mrun[q] = mnew;
        }
#pragma unroll
        for (int dt = 0; dt < 4; dt++) {
            oacc[dt][0] *= fac[0]; oacc[dt][1] *= fac[1];
            oacc[dt][2] *= fac[2]; oacc[dt][3] *= fac[3];
        }
        // ---- P -> LDS (bf16), 8-elem-chunk XOR swizzle, D-layout -> A-layout ----
#pragma unroll
        for (int t = 0; t < 8; t++) {
#pragma unroll
            for (int q = 0; q < 4; q++) {
                int rl = hi * 4 + q;
                int c = t * 16 + lo;
                int cs = (((c >> 3) ^ (rl & 7)) << 3) | (c & 7);
                p_lds[wid][rl][cs] = (bf16)st[t][q];
            }
        }
        // ---- PV: A = P from LDS, B = vT rows (contiguous) ----
#pragma unroll
        for (int ks = 0; ks < 4; ks++) {
            int chunk = (ks * 4 + hi) ^ (lo & 7);
            bf16x8 pa = *(const bf16x8*)&p_lds[wid][lo][chunk << 3];
#pragma unroll
            for (int dt = 0; dt < 4; dt++) {
                bf16x8 vf = *(const bf16x8*)(vbase + (size_t)(dt * 16 + lo) * 512 + m0 + ks * 32 + hi * 8);
                mfma16(oacc[dt], pa, vf);
            }
        }
    }
    asm volatile("s_nop 7\n\ts_nop 7");
    // ---- epilogue: normalize, bounce through LDS, coalesced bf16 write ----
    float inv[4];
#pragma unroll
    for (int q = 0; q < 4; q++) inv[q] = 1.f / lrun[q];
#pragma unroll
    for (int dt = 0; dt < 4; dt++)
#pragma unroll
        for (int q = 0; q < 4; q++)
            o_lds[wid][hi * 4 + q][dt * 16 + lo] = (bf16)(oacc[dt][q] * inv[q]);
    {
        int r = lane >> 2, c = (lane & 3) * 16;
        bf16x8 w0 = *(const bf16x8*)&o_lds[wid][r][c];
        bf16x8 w1 = *(const bf16x8*)&o_lds[wid][r][c + 8];
        bf16* op = out + (size_t)(b * 512 + n0 + r) * 512 + h * 64 + c;
        *(bf16x8*)op = w0;
        *(bf16x8*)(op + 8) = w1;
    }
}

// ---------------- gather masked positions (f32 out + bf16 copy) ----------------
__global__ __launch_bounds__(256) void gather_kernel(
        const float* __restrict__ x, const int* __restrict__ mp,
        float* __restrict__ h1, bf16* __restrict__ h1b) {
    int idx = blockIdx.x * 256 + threadIdx.x;
    int row = idx >> 7, c4 = (idx & 127) * 4;
    int b = row >> 6;
    int src = mp[row];
    float4 v = *(const float4*)&x[((size_t)(b * 512 + src)) * 512 + c4];
    *(float4*)&h1[(size_t)row * 512 + c4] = v;
    bf16x4 p;
    p[0] = (bf16)v.x; p[1] = (bf16)v.y; p[2] = (bf16)v.z; p[3] = (bf16)v.w;
    *(bf16x4*)&h1b[(size_t)row * 512 + c4] = p;
}

// ---------------- final decoder dot (512 -> 1) ----------------
__global__ __launch_bounds__(256) void dec2_kernel(
        const float* __restrict__ dmid, const float* __restrict__ w2,
        const float* __restrict__ b2, float* __restrict__ out) {
    const int lane = threadIdx.x & 63;
    const int row = blockIdx.x * 4 + (threadIdx.x >> 6);
    float s = 0.f;
#pragma unroll
    for (int t = 0; t < 8; t++) {
        int c = lane + t * 64;
        s = fmaf(dmid[(size_t)row * 512 + c], w2[c], s);
    }
#pragma unroll
    for (int off = 32; off >= 1; off >>= 1) s += __shfl_xor(s, off);
    if (lane == 0) out[row] = s + b2[0];
}

extern "C" void kernel_launch(void* const* d_in, const int* in_sizes, int n_in,
                              void* d_out, int out_size, void* d_ws, size_t ws_size,
                              hipStream_t stream) {
    const float* feat   = (const float*)d_in[0];
    const float* rpos   = (const float*)d_in[1];
    const int*   mpos   = (const int*)d_in[2];
    const float* fe_w1  = (const float*)d_in[3];
    const float* fe_b1  = (const float*)d_in[4];
    const float* fe_w2  = (const float*)d_in[5];
    const float* fe_b2  = (const float*)d_in[6];
    const float* wq     = (const float*)d_in[7];
    const float* bq     = (const float*)d_in[8];
    const float* wk     = (const float*)d_in[9];
    const float* bk     = (const float*)d_in[10];
    const float* wv     = (const float*)d_in[11];
    const float* bv     = (const float*)d_in[12];
    const float* wp     = (const float*)d_in[13];
    const float* bp     = (const float*)d_in[14];
    const float* wo     = (const float*)d_in[15];
    const float* bo     = (const float*)d_in[16];
    const float* ln1_g  = (const float*)d_in[17];
    const float* ln1_b  = (const float*)d_in[18];
    const float* ffn_w1 = (const float*)d_in[19];
    const float* ffn_b1 = (const float*)d_in[20];
    const float* ffn_w2 = (const float*)d_in[21];
    const float* ffn_b2 = (const float*)d_in[22];
    const float* ln2_g  = (const float*)d_in[23];
    const float* ln2_b  = (const float*)d_in[24];
    const float* ln_g   = (const float*)d_in[25];
    const float* ln_b   = (const float*)d_in[26];
    const float* lin_w  = (const float*)d_in[27];
    const float* lin_b  = (const float*)d_in[28];
    const float* dec_w1 = (const float*)d_in[29];
    const float* dec_b1 = (const float*)d_in[30];
    const float* dec_w2 = (const float*)d_in[31];
    const float* dec_b2 = (const float*)d_in[32];

    char* W = (char*)d_ws;
    float* f_x    = (float*)(W);
    bf16*  qkvb   = (bf16*)(W + 16777216);
    bf16*  tb     = (bf16*)(W + 41943040);
    bf16*  midb   = (bf16*)(W + 16777216);   // aliases qkvb+tb (dead during FFN)
    bf16*  xb     = (bf16*)(W + 50331648);
    bf16*  kPb    = (bf16*)(W + 50331648);   // reuses xb region (xb dead post-QKV)
    bf16*  vTb    = (bf16*)(W + 58720256);
    bf16*  wTall  = (bf16*)(W + 67108864);
    float* qkbias = (float*)(W + 93847552);
    bf16*  h1b    = tb;
    bf16*  h2b    = tb + 524288;

    bf16* feT  = wTall + 12582912;
    bf16* linT = wTall + 12845056;
    bf16* decT = wTall + 13107200;

    float* outp  = (float*)d_out;
    float* o_dec = outp;                      // (16,64,1)
    float* o_h1  = outp + 1024;               // (16,64,512)
    float* o_h2  = outp + 1024 + 524288;      // (16,64,512)

    dim3 g512(4, 64), gQKV(12, 64), gF1(16, 64), gsm(4, 8);

    packb_kernel<<<24, 256, 0, stream>>>(bq, bk, bv, qkbias);
    transall_kernel<<<13056, 256, 0, stream>>>(fe_w2, wq, wk, wv, wo, ffn_w1, ffn_w2,
                                               lin_w, dec_w1, wTall);

    // feature encoder + shared LN
    fe1_kernel<<<16384, 256, 0, stream>>>(feat, fe_w1, fe_b1, tb);
    mm_kernel<0, true, false><<<g512, 256, 0, stream>>>(tb, feT, fe_b2, nullptr, f_x, nullptr, 8192, 512, 512);
    ln_kernel<<<2048, 256, 0, stream>>>(f_x, f_x, xb, ln_g, ln_b);

    for (int l = 0; l < 4; l++) {
        bf16* qT  = wTall + (size_t)l * 3145728;
        bf16* oT  = qT + 786432;
        bf16* w1T = qT + 1048576;
        bf16* w2T = qT + 2097152;

        mm_kernel<0, false, true><<<gQKV, 256, 0, stream>>>(xb, qT, qkbias + l * 1536, nullptr, nullptr, qkvb, 8192, 1536, 512);
        vt_kernel<<<dim3(16, 2, 128), 256, 0, stream>>>(qkvb, vTb, kPb);   // clobbers xb
        attn_kernel<<<dim3(32, 16), 512, 0, stream>>>(qkvb, kPb, vTb, rpos,
                                                      wp + (size_t)l * 1536, bp + (size_t)l * 512, tb);
        mm_kernel<0, true, false><<<g512, 256, 0, stream>>>(tb, oT, bo + l * 512, f_x, f_x, nullptr, 8192, 512, 512);
        ln_kernel<<<2048, 256, 0, stream>>>(f_x, f_x, xb, ln1_g + l * 512, ln1_b + l * 512);
        mm_kernel<1, false, true><<<gF1, 256, 0, stream>>>(xb, w1T, ffn_b1 + l * 2048, nullptr, nullptr, midb, 8192, 2048, 512);
        mm_kernel<0, true, false><<<g512, 256, 0, stream>>>(midb, w2T, ffn_b2 + l * 512, f_x, f_x, nullptr, 8192, 512, 2048);
        ln_kernel<<<2048, 256, 0, stream>>>(f_x, f_x, xb, ln2_g + l * 512, ln2_b + l * 512);
    }

    // masked gather + heads
    gather_kernel<<<512, 256, 0, stream>>>(f_x, mpos, o_h1, h1b);
    mm_kernel<2, true, false><<<gsm, 256, 0, stream>>>(h1b, linT, lin_b, nullptr, f_x, nullptr, 1024, 512, 512);
    ln_kernel<<<256, 256, 0, stream>>>(f_x, o_h2, h2b, ln_g, ln_b);
    mm_kernel<0, true, false><<<gsm, 256, 0, stream>>>(h2b, decT, dec_b1, nullptr, f_x, nullptr, 1024, 512, 512);
    dec2_kernel<<<256, 256, 0, stream>>>(f_x, dec_w2, dec_b2, o_dec);
}

// Round 8
// 1250.700 us; speedup vs baseline: 1.2601x; 1.2523x over previous
//
#include <hip/hip_runtime.h>
#include <hip/hip_bf16.h>
#include <math.h>

// SpaFormer forward. bf16-MFMA GEMMs + head-shared-rpos MFMA attention
// (R8: wide load batches + 256-VGPR headroom in attn).
// B=16 N=512 L=4 H=8 DK=DV=64 DM=512 DI=2048 M=64
//
// ws layout (bytes), total 93.9 MB:
//   f_x   f32  @ 0           16,777,216  (x stream, in-place LN)
//   qkvb  bf16 @ 16,777,216  25,165,824  ([8192][1536] fused q|k|v)
//   tb    bf16 @ 41,943,040   8,388,608  (fe1 out / attn out; h1b/h2b later)
//   midb  bf16 @ 16,777,216  33,554,432  (FFN mid; aliases qkvb+tb, dead then)
//   xb    bf16 @ 50,331,648   8,388,608  (bf16 x; reused as kP during attn)
//   vT    bf16 @ 58,720,256   8,388,608  ([bh][64][512] transposed V)
//   wTall bf16 @ 67,108,864  26,738,688  (ALL transposed weights)
//   qkbias f32 @ 93,847,552      24,576

using bf16   = __bf16;
using bf16x4 = __attribute__((ext_vector_type(4))) __bf16;
using bf16x8 = __attribute__((ext_vector_type(8))) __bf16;
using f32x4  = __attribute__((ext_vector_type(4))) float;

__device__ __forceinline__ void mfma16(f32x4& d, bf16x8 a, bf16x8 b) {
    // D(16x16) = A(16x32)*B(32x16)+D. A/B: lane holds row/col (lane&15),
    // k = (lane>>4)*8+0..7. D: col=lane&15, row=(lane>>4)*4+reg.
    asm("v_mfma_f32_16x16x32_bf16 %0, %1, %2, %0" : "+v"(d) : "v"(a), "v"(b));
}

// ---------------- pack bq|bk|bv into [L][1536] ----------------
__global__ __launch_bounds__(256) void packb_kernel(
        const float* __restrict__ bq, const float* __restrict__ bk,
        const float* __restrict__ bv, float* __restrict__ out) {
    int i = blockIdx.x * 256 + threadIdx.x;
    if (i >= 6144) return;
    int l = i / 1536, c = i % 1536;
    out[i] = c < 512 ? bq[l * 512 + c] : c < 1024 ? bk[l * 512 + c - 512]
                                                  : bv[l * 512 + c - 1024];
}

// ---------------- ALL weight transposes, fp32 [K][N] -> bf16 [N][K] ----------------
__global__ __launch_bounds__(256) void transall_kernel(
        const float* __restrict__ fe_w2, const float* __restrict__ wq,
        const float* __restrict__ wk, const float* __restrict__ wv,
        const float* __restrict__ wo, const float* __restrict__ w1,
        const float* __restrict__ w2, const float* __restrict__ lin_w,
        const float* __restrict__ dec_w1, bf16* __restrict__ dst) {
    __shared__ float t[32][33];
    int id = blockIdx.x;
    const float* src; bf16* d; int K, N, ti;
    if (id < 256)        { src = fe_w2;  d = dst + 12582912; K = 512; N = 512; ti = id; }
    else if (id < 12544) {
        int u = id - 256, l = u / 3072, r = u % 3072;
        bf16* base = dst + (size_t)l * 3145728;
        if      (r < 256)  { src = wq + (size_t)l * 262144;  d = base;           K = 512;  N = 512;  ti = r; }
        else if (r < 512)  { src = wk + (size_t)l * 262144;  d = base + 262144;  K = 512;  N = 512;  ti = r - 256; }
        else if (r < 768)  { src = wv + (size_t)l * 262144;  d = base + 524288;  K = 512;  N = 512;  ti = r - 512; }
        else if (r < 1024) { src = wo + (size_t)l * 262144;  d = base + 786432;  K = 512;  N = 512;  ti = r - 768; }
        else if (r < 2048) { src = w1 + (size_t)l * 1048576; d = base + 1048576; K = 512;  N = 2048; ti = r - 1024; }
        else               { src = w2 + (size_t)l * 1048576; d = base + 2097152; K = 2048; N = 512;  ti = r - 2048; }
    }
    else if (id < 12800) { src = lin_w;  d = dst + 12845056; K = 512; N = 512; ti = id - 12544; }
    else                 { src = dec_w1; d = dst + 13107200; K = 512; N = 512; ti = id - 12800; }
    int nt = N >> 5;
    int n0 = (ti % nt) * 32, k0 = (ti / nt) * 32;
    int tx = threadIdx.x & 31, ty = threadIdx.x >> 5;
#pragma unroll
    for (int i = 0; i < 4; i++)
        t[ty + i * 8][tx] = src[(size_t)(k0 + ty + i * 8) * N + n0 + tx];
    __syncthreads();
#pragma unroll
    for (int i = 0; i < 4; i++)
        d[(size_t)(n0 + ty + i * 8) * K + k0 + tx] = (bf16)t[tx][ty + i * 8];
}

// ---------------- V transpose + K pack: vT[bh][64][512], kP[bh][512][64] ----------------
__global__ __launch_bounds__(256) void vt_kernel(
        const bf16* __restrict__ qkv, bf16* __restrict__ vT, bf16* __restrict__ kP) {
    __shared__ bf16 t[32][33];
    int s = blockIdx.z;                      // b*8+h
    int m0 = blockIdx.x * 32, d0 = blockIdx.y * 32;
    int tx = threadIdx.x & 31, ty = threadIdx.x >> 5;
    int b = s >> 3, h = s & 7;
    const bf16* srcv = qkv + 1024 + (size_t)h * 64;
    const bf16* srck = qkv + 512 + (size_t)h * 64;
#pragma unroll
    for (int i = 0; i < 4; i++) {
        int m = m0 + ty + i * 8;
        t[ty + i * 8][tx] = srcv[(size_t)(b * 512 + m) * 1536 + d0 + tx];
        kP[((size_t)s * 512 + m) * 64 + d0 + tx] =
            srck[(size_t)(b * 512 + m) * 1536 + d0 + tx];
    }
    __syncthreads();
#pragma unroll
    for (int i = 0; i < 4; i++)
        vT[((size_t)s * 64 + d0 + ty + i * 8) * 512 + m0 + tx] = t[tx][ty + i * 8];
}

// ---------------- feature-encoder first linear (K=3), bf16 out ----------------
__global__ __launch_bounds__(256) void fe1_kernel(
        const float* __restrict__ feat, const float* __restrict__ w1,
        const float* __restrict__ b1, bf16* __restrict__ out) {
    int idx = blockIdx.x * 256 + threadIdx.x;
    int r = idx >> 9, j = idx & 511;
    float f0 = feat[r * 3 + 0], f1 = feat[r * 3 + 1], f2 = feat[r * 3 + 2];
    out[(size_t)r * 512 + j] = (bf16)
        fmaf(f0, w1[j], fmaf(f1, w1[512 + j], fmaf(f2, w1[1024 + j], b1[j])));
}

// ---------------- bf16 MFMA GEMM (proven) ----------------
template<int EPI, bool WF32, bool WB16>
__global__ __launch_bounds__(256) void mm_kernel(
        const bf16* __restrict__ A, const bf16* __restrict__ Bt,
        const float* __restrict__ bias, const float* __restrict__ res,
        float* __restrict__ Cf, bf16* __restrict__ Cb,
        int M, int N, int K) {
    __shared__ bf16 Al[2][8192];
    __shared__ bf16 Bl[2][8192];
    const int tid = threadIdx.x;
    const int lane = tid & 63, wid = tid >> 6;
    const int r0 = blockIdx.y * 128, c0 = blockIdx.x * 128;
    const int wr = (wid >> 1) * 64, wc = (wid & 1) * 64;

    f32x4 acc[4][4] = {};
    const int kTiles = K >> 6;

#define STAGE(buf, kt)                                                                   \
    {                                                                                    \
        const bf16* ga = A + (size_t)r0 * K + (kt) * 64;                                 \
        const bf16* gb = Bt + (size_t)c0 * K + (kt) * 64;                                \
        _Pragma("unroll")                                                                \
        for (int i_ = 0; i_ < 4; i_++) {                                                 \
            int s = tid + i_ * 256;                                                      \
            int row = s >> 3;                                                            \
            int ssl = (s & 7) ^ (row & 7);                                               \
            __builtin_amdgcn_global_load_lds(                                            \
                (const __attribute__((address_space(1))) void*)(ga + (size_t)row * K + ssl * 8), \
                (__attribute__((address_space(3))) void*)(&Al[buf][s * 8]), 16, 0, 0);   \
            __builtin_amdgcn_global_load_lds(                                            \
                (const __attribute__((address_space(1))) void*)(gb + (size_t)row * K + ssl * 8), \
                (__attribute__((address_space(3))) void*)(&Bl[buf][s * 8]), 16, 0, 0);   \
        }                                                                                \
    }

    STAGE(0, 0);
    __syncthreads();

    for (int kt = 0; kt < kTiles; kt++) {
        if (kt + 1 < kTiles) STAGE((kt + 1) & 1, kt + 1);
        const bf16* al = Al[kt & 1];
        const bf16* bl = Bl[kt & 1];
#pragma unroll
        for (int kk = 0; kk < 2; kk++) {
            bf16x8 af[4], bfr[4];
#pragma unroll
            for (int i = 0; i < 4; i++) {
                int arow = wr + i * 16 + (lane & 15);
                int slot = kk * 4 + (lane >> 4);
                af[i] = *(const bf16x8*)(al + arow * 64 + ((slot ^ (arow & 7)) << 3));
                int brow = wc + i * 16 + (lane & 15);
                bfr[i] = *(const bf16x8*)(bl + brow * 64 + ((slot ^ (brow & 7)) << 3));
            }
#pragma unroll
            for (int i = 0; i < 4; i++)
#pragma unroll
                for (int j = 0; j < 4; j++)
                    mfma16(acc[i][j], af[i], bfr[j]);
        }
        __syncthreads();
    }
#undef STAGE

    asm volatile("s_nop 7\n\ts_nop 7");

#pragma unroll
    for (int i = 0; i < 4; i++)
#pragma unroll
        for (int j = 0; j < 4; j++)
#pragma unroll
            for (int q = 0; q < 4; q++) {
                int row = r0 + wr + i * 16 + ((lane >> 4) << 2) + q;
                int col = c0 + wc + j * 16 + (lane & 15);
                float v = acc[i][j][q] + bias[col];
                if (res) v += res[(size_t)row * N + col];
                if (EPI == 1) v = fmaxf(v, 0.f);
                if (EPI == 2) v = 0.5f * v * (1.f + erff(v * 0.7071067811865475f));
                if (WF32) Cf[(size_t)row * N + col] = v;
                if (WB16) Cb[(size_t)row * N + col] = (bf16)v;
            }
}

// ---------------- LayerNorm over 512 (in-place capable), f32 + bf16 out ----------------
__global__ __launch_bounds__(256) void ln_kernel(
        const float* __restrict__ in, float* __restrict__ outf, bf16* __restrict__ outb,
        const float* __restrict__ g, const float* __restrict__ b) {
    const int lane = threadIdx.x & 63;
    const size_t row = (size_t)blockIdx.x * 4 + (threadIdx.x >> 6);
    const float* x = in + row * 512;
    float4 a0 = *(const float4*)&x[lane * 4];
    float4 a1 = *(const float4*)&x[256 + lane * 4];
    float s = a0.x + a0.y + a0.z + a0.w + a1.x + a1.y + a1.z + a1.w;
#pragma unroll
    for (int off = 32; off >= 1; off >>= 1) s += __shfl_xor(s, off);
    float mean = s * (1.f / 512.f);
    float d, vs = 0.f;
    d = a0.x - mean; vs += d * d;  d = a0.y - mean; vs += d * d;
    d = a0.z - mean; vs += d * d;  d = a0.w - mean; vs += d * d;
    d = a1.x - mean; vs += d * d;  d = a1.y - mean; vs += d * d;
    d = a1.z - mean; vs += d * d;  d = a1.w - mean; vs += d * d;
#pragma unroll
    for (int off = 32; off >= 1; off >>= 1) vs += __shfl_xor(vs, off);
    float inv = rsqrtf(vs * (1.f / 512.f) + 1e-6f);
    float4 g0 = *(const float4*)&g[lane * 4];
    float4 g1 = *(const float4*)&g[256 + lane * 4];
    float4 b0 = *(const float4*)&b[lane * 4];
    float4 b1v = *(const float4*)&b[256 + lane * 4];
    float o[8];
    o[0] = (a0.x - mean) * inv * g0.x + b0.x;
    o[1] = (a0.y - mean) * inv * g0.y + b0.y;
    o[2] = (a0.z - mean) * inv * g0.z + b0.z;
    o[3] = (a0.w - mean) * inv * g0.w + b0.w;
    o[4] = (a1.x - mean) * inv * g1.x + b1v.x;
    o[5] = (a1.y - mean) * inv * g1.y + b1v.y;
    o[6] = (a1.z - mean) * inv * g1.z + b1v.z;
    o[7] = (a1.w - mean) * inv * g1.w + b1v.w;
    float* y = outf + row * 512;
    *(float4*)&y[lane * 4] = make_float4(o[0], o[1], o[2], o[3]);
    *(float4*)&y[256 + lane * 4] = make_float4(o[4], o[5], o[6], o[7]);
    bf16x4 p0, p1;
#pragma unroll
    for (int i = 0; i < 4; i++) { p0[i] = (bf16)o[i]; p1[i] = (bf16)o[4 + i]; }
    *(bf16x4*)&outb[row * 512 + lane * 4] = p0;
    *(bf16x4*)&outb[row * 512 + 256 + lane * 4] = p1;
}

// ---------------- MFMA attention, head-shared rpos, wide load batches ----------------
// grid (32 qtiles, 16 b), 512 threads = 8 waves, wave = head.
// R8: __launch_bounds__(512,2) for 256-VGPR headroom; K loads batched (16 in
// flight) before QK^T MFMAs; V loads batched right after QK^T, consumed after
// softmax (latency hidden under rel+softmax VALU work).
__global__ __launch_bounds__(512, 2) void attn_kernel(
        const bf16* __restrict__ qb, const bf16* __restrict__ kP,
        const bf16* __restrict__ vT, const float* __restrict__ rpos,
        const float* __restrict__ wp, const float* __restrict__ bp,
        bf16* __restrict__ out) {
    __shared__ float rp_lds[3][16][132];   // padded pitch 132
    __shared__ float qw_lds[8][16][4];
    __shared__ bf16 p_lds[8][16][128];     // XOR-swizzled P tile per wave
    __shared__ bf16 o_lds[8][16][64];
    const int tid = threadIdx.x, lane = tid & 63, wid = tid >> 6;
    const int b = blockIdx.y, h = wid;
    const int n0 = blockIdx.x * 16;
    const int lo = lane & 15, hi = lane >> 4;
    const float scale = 0.125f;

    const bf16* qbase = qb + (size_t)(b * 512) * 1536 + h * 64;
    const bf16* kbase = kP + ((size_t)(b * 8 + h)) * 32768;   // [512][64]
    const bf16* vbase = vT + ((size_t)(b * 8 + h)) * 32768;   // [64][512]
    const float* rbase = rpos + (size_t)(b * 512 + n0) * 1536;

    // qw3 per row (per wave/head): lane -> (r = lane>>2, j = lane&3)
    {
        int r = lane >> 2, j = lane & 3;
        const float* wvec = (j < 3) ? wp + ((size_t)j * 8 + h) * 64 : bp + (size_t)h * 64;
        const bf16* qr = qbase + (size_t)(n0 + r) * 1536;
        float s = 0.f;
#pragma unroll
        for (int c8 = 0; c8 < 8; c8++) {
            bf16x8 v8 = *(const bf16x8*)(qr + c8 * 8);
#pragma unroll
            for (int i = 0; i < 8; i++) s = fmaf((float)v8[i], wvec[c8 * 8 + i], s);
        }
        qw_lds[wid][r][j] = s;
    }
    bf16x8 af0 = *(const bf16x8*)(qbase + (size_t)(n0 + lo) * 1536 + hi * 8);
    bf16x8 af1 = *(const bf16x8*)(qbase + (size_t)(n0 + lo) * 1536 + 32 + hi * 8);
    float qw[4][4];
#pragma unroll
    for (int q = 0; q < 4; q++)
#pragma unroll
        for (int j = 0; j < 4; j++) qw[q][j] = qw_lds[wid][hi * 4 + q][j];

    f32x4 oacc[4] = {};
    float mrun[4] = {-1e30f, -1e30f, -1e30f, -1e30f};
    float lrun[4] = {0.f, 0.f, 0.f, 0.f};

    for (int mc = 0; mc < 4; mc++) {
        const int m0 = mc * 128;
        // ---- stage rpos chunk: [16 rows][128 m][3] -> planes [p][r][m] ----
        __syncthreads();   // prior chunk's rel reads done before overwrite
#pragma unroll
        for (int k = 0; k < 12; k++) {
            int flat = tid + k * 512;            // 0..6143
            int r = flat / 384, rem = flat % 384;
            float v = rbase[(size_t)r * 1536 + m0 * 3 + rem];
            rp_lds[rem % 3][r][rem / 3] = v;
        }
        __syncthreads();
        // ---- QK^T: batch ALL 16 K-fragment loads, then 16 MFMAs ----
        bf16x8 kfs[16];
#pragma unroll
        for (int t = 0; t < 8; t++) {
            const bf16* kr = kbase + (size_t)(m0 + t * 16 + lo) * 64 + hi * 8;
            kfs[t * 2]     = *(const bf16x8*)kr;
            kfs[t * 2 + 1] = *(const bf16x8*)(kr + 32);
        }
        f32x4 st[8];
#pragma unroll
        for (int t = 0; t < 8; t++) {
            f32x4 z = {};
            mfma16(z, af0, kfs[t * 2]);
            mfma16(z, af1, kfs[t * 2 + 1]);
            st[t] = z;
        }
        // ---- V loads issued EARLY (consumed after softmax): 16 in flight ----
        bf16x8 vfs[16];
#pragma unroll
        for (int ks = 0; ks < 4; ks++)
#pragma unroll
            for (int dt = 0; dt < 4; dt++)
                vfs[ks * 4 + dt] = *(const bf16x8*)
                    (vbase + (size_t)(dt * 16 + lo) * 512 + m0 + ks * 32 + hi * 8);
        asm volatile("s_nop 7\n\ts_nop 7");   // MFMA->VALU hazard
        // ---- rel from LDS: st += qw . rp ----
#pragma unroll
        for (int t = 0; t < 8; t++) {
#pragma unroll
            for (int q = 0; q < 4; q++) {
                int r = hi * 4 + q, m = t * 16 + lo;
                st[t][q] += fmaf(qw[q][0], rp_lds[0][r][m],
                             fmaf(qw[q][1], rp_lds[1][r][m],
                              fmaf(qw[q][2], rp_lds[2][r][m], qw[q][3])));
            }
        }
        // ---- online softmax (rows = hi*4+q, cross-lane over lo nibble) ----
        float fac[4];
#pragma unroll
        for (int q = 0; q < 4; q++) {
            float mx = st[0][q];
#pragma unroll
            for (int t = 1; t < 8; t++) mx = fmaxf(mx, st[t][q]);
            mx = fmaxf(mx, __shfl_xor(mx, 1));
            mx = fmaxf(mx, __shfl_xor(mx, 2));
            mx = fmaxf(mx, __shfl_xor(mx, 4));
            mx = fmaxf(mx, __shfl_xor(mx, 8));
            float mnew = fmaxf(mrun[q], mx);
            fac[q] = __expf((mrun[q] - mnew) * scale);
            float ls = 0.f;
#pragma unroll
            for (int t = 0; t < 8; t++) {
                float e = __expf((st[t][q] - mnew) * scale);
                st[t][q] = e;
                ls += e;
            }
            ls += __shfl_xor(ls, 1);
            ls += __shfl_xor(ls, 2);
            ls += __shfl_xor(ls, 4);
            ls += __shfl_xor(ls, 8);
            lrun[q] = lrun[q] * fac[q] + ls;
            mrun[q] = mnew;
        }
#pragma unroll
        for (int dt = 0; dt < 4; dt++) {
            oacc[dt][0] *= fac[0]; oacc[dt][1] *= fac[1];
            oacc[dt][2] *= fac[2]; oacc[dt][3] *= fac[3];
        }
        // ---- P -> LDS (bf16), 8-elem-chunk XOR swizzle, D-layout -> A-layout ----
#pragma unroll
        for (int t = 0; t < 8; t++) {
#pragma unroll
            for (int q = 0; q < 4; q++) {
                int rl = hi * 4 + q;
                int c = t * 16 + lo;
                int cs = (((c >> 3) ^ (rl & 7)) << 3) | (c & 7);
                p_lds[wid][rl][cs] = (bf16)st[t][q];
            }
        }
        // ---- PV: A = P from LDS, B = vfs (already resident) ----
#pragma unroll
        for (int ks = 0; ks < 4; ks++) {
            int chunk = (ks * 4 + hi) ^ (lo & 7);
            bf16x8 pa = *(const bf16x8*)&p_lds[wid][lo][chunk << 3];
#pragma unroll
            for (int dt = 0; dt < 4; dt++)
                mfma16(oacc[dt], pa, vfs[ks * 4 + dt]);
        }
    }
    asm volatile("s_nop 7\n\ts_nop 7");
    // ---- epilogue: normalize, bounce through LDS, coalesced bf16 write ----
    float inv[4];
#pragma unroll
    for (int q = 0; q < 4; q++) inv[q] = 1.f / lrun[q];
#pragma unroll
    for (int dt = 0; dt < 4; dt++)
#pragma unroll
        for (int q = 0; q < 4; q++)
            o_lds[wid][hi * 4 + q][dt * 16 + lo] = (bf16)(oacc[dt][q] * inv[q]);
    {
        int r = lane >> 2, c = (lane & 3) * 16;
        bf16x8 w0 = *(const bf16x8*)&o_lds[wid][r][c];
        bf16x8 w1 = *(const bf16x8*)&o_lds[wid][r][c + 8];
        bf16* op = out + (size_t)(b * 512 + n0 + r) * 512 + h * 64 + c;
        *(bf16x8*)op = w0;
        *(bf16x8*)(op + 8) = w1;
    }
}

// ---------------- gather masked positions (f32 out + bf16 copy) ----------------
__global__ __launch_bounds__(256) void gather_kernel(
        const float* __restrict__ x, const int* __restrict__ mp,
        float* __restrict__ h1, bf16* __restrict__ h1b) {
    int idx = blockIdx.x * 256 + threadIdx.x;
    int row = idx >> 7, c4 = (idx & 127) * 4;
    int b = row >> 6;
    int src = mp[row];
    float4 v = *(const float4*)&x[((size_t)(b * 512 + src)) * 512 + c4];
    *(float4*)&h1[(size_t)row * 512 + c4] = v;
    bf16x4 p;
    p[0] = (bf16)v.x; p[1] = (bf16)v.y; p[2] = (bf16)v.z; p[3] = (bf16)v.w;
    *(bf16x4*)&h1b[(size_t)row * 512 + c4] = p;
}

// ---------------- final decoder dot (512 -> 1) ----------------
__global__ __launch_bounds__(256) void dec2_kernel(
        const float* __restrict__ dmid, const float* __restrict__ w2,
        const float* __restrict__ b2, float* __restrict__ out) {
    const int lane = threadIdx.x & 63;
    const int row = blockIdx.x * 4 + (threadIdx.x >> 6);
    float s = 0.f;
#pragma unroll
    for (int t = 0; t < 8; t++) {
        int c = lane + t * 64;
        s = fmaf(dmid[(size_t)row * 512 + c], w2[c], s);
    }
#pragma unroll
    for (int off = 32; off >= 1; off >>= 1) s += __shfl_xor(s, off);
    if (lane == 0) out[row] = s + b2[0];
}

extern "C" void kernel_launch(void* const* d_in, const int* in_sizes, int n_in,
                              void* d_out, int out_size, void* d_ws, size_t ws_size,
                              hipStream_t stream) {
    const float* feat   = (const float*)d_in[0];
    const float* rpos   = (const float*)d_in[1];
    const int*   mpos   = (const int*)d_in[2];
    const float* fe_w1  = (const float*)d_in[3];
    const float* fe_b1  = (const float*)d_in[4];
    const float* fe_w2  = (const float*)d_in[5];
    const float* fe_b2  = (const float*)d_in[6];
    const float* wq     = (const float*)d_in[7];
    const float* bq     = (const float*)d_in[8];
    const float* wk     = (const float*)d_in[9];
    const float* bk     = (const float*)d_in[10];
    const float* wv     = (const float*)d_in[11];
    const float* bv     = (const float*)d_in[12];
    const float* wp     = (const float*)d_in[13];
    const float* bp     = (const float*)d_in[14];
    const float* wo     = (const float*)d_in[15];
    const float* bo     = (const float*)d_in[16];
    const float* ln1_g  = (const float*)d_in[17];
    const float* ln1_b  = (const float*)d_in[18];
    const float* ffn_w1 = (const float*)d_in[19];
    const float* ffn_b1 = (const float*)d_in[20];
    const float* ffn_w2 = (const float*)d_in[21];
    const float* ffn_b2 = (const float*)d_in[22];
    const float* ln2_g  = (const float*)d_in[23];
    const float* ln2_b  = (const float*)d_in[24];
    const float* ln_g   = (const float*)d_in[25];
    const float* ln_b   = (const float*)d_in[26];
    const float* lin_w  = (const float*)d_in[27];
    const float* lin_b  = (const float*)d_in[28];
    const float* dec_w1 = (const float*)d_in[29];
    const float* dec_b1 = (const float*)d_in[30];
    const float* dec_w2 = (const float*)d_in[31];
    const float* dec_b2 = (const float*)d_in[32];

    char* W = (char*)d_ws;
    float* f_x    = (float*)(W);
    bf16*  qkvb   = (bf16*)(W + 16777216);
    bf16*  tb     = (bf16*)(W + 41943040);
    bf16*  midb   = (bf16*)(W + 16777216);   // aliases qkvb+tb (dead during FFN)
    bf16*  xb     = (bf16*)(W + 50331648);
    bf16*  kPb    = (bf16*)(W + 50331648);   // reuses xb region (xb dead post-QKV)
    bf16*  vTb    = (bf16*)(W + 58720256);
    bf16*  wTall  = (bf16*)(W + 67108864);
    float* qkbias = (float*)(W + 93847552);
    bf16*  h1b    = tb;
    bf16*  h2b    = tb + 524288;

    bf16* feT  = wTall + 12582912;
    bf16* linT = wTall + 12845056;
    bf16* decT = wTall + 13107200;

    float* outp  = (float*)d_out;
    float* o_dec = outp;                      // (16,64,1)
    float* o_h1  = outp + 1024;               // (16,64,512)
    float* o_h2  = outp + 1024 + 524288;      // (16,64,512)

    dim3 g512(4, 64), gQKV(12, 64), gF1(16, 64), gsm(4, 8);

    packb_kernel<<<24, 256, 0, stream>>>(bq, bk, bv, qkbias);
    transall_kernel<<<13056, 256, 0, stream>>>(fe_w2, wq, wk, wv, wo, ffn_w1, ffn_w2,
                                               lin_w, dec_w1, wTall);

    // feature encoder + shared LN
    fe1_kernel<<<16384, 256, 0, stream>>>(feat, fe_w1, fe_b1, tb);
    mm_kernel<0, true, false><<<g512, 256, 0, stream>>>(tb, feT, fe_b2, nullptr, f_x, nullptr, 8192, 512, 512);
    ln_kernel<<<2048, 256, 0, stream>>>(f_x, f_x, xb, ln_g, ln_b);

    for (int l = 0; l < 4; l++) {
        bf16* qT  = wTall + (size_t)l * 3145728;
        bf16* oT  = qT + 786432;
        bf16* w1T = qT + 1048576;
        bf16* w2T = qT + 2097152;

        mm_kernel<0, false, true><<<gQKV, 256, 0, stream>>>(xb, qT, qkbias + l * 1536, nullptr, nullptr, qkvb, 8192, 1536, 512);
        vt_kernel<<<dim3(16, 2, 128), 256, 0, stream>>>(qkvb, vTb, kPb);   // clobbers xb
        attn_kernel<<<dim3(32, 16), 512, 0, stream>>>(qkvb, kPb, vTb, rpos,
                                                      wp + (size_t)l * 1536, bp + (size_t)l * 512, tb);
        mm_kernel<0, true, false><<<g512, 256, 0, stream>>>(tb, oT, bo + l * 512, f_x, f_x, nullptr, 8192, 512, 512);
        ln_kernel<<<2048, 256, 0, stream>>>(f_x, f_x, xb, ln1_g + l * 512, ln1_b + l * 512);
        mm_kernel<1, false, true><<<gF1, 256, 0, stream>>>(xb, w1T, ffn_b1 + l * 2048, nullptr, nullptr, midb, 8192, 2048, 512);
        mm_kernel<0, true, false><<<g512, 256, 0, stream>>>(midb, w2T, ffn_b2 + l * 512, f_x, f_x, nullptr, 8192, 512, 2048);
        ln_kernel<<<2048, 256, 0, stream>>>(f_x, f_x, xb, ln2_g + l * 512, ln2_b + l * 512);
    }

    // masked gather + heads
    gather_kernel<<<512, 256, 0, stream>>>(f_x, mpos, o_h1, h1b);
    mm_kernel<2, true, false><<<gsm, 256, 0, stream>>>(h1b, linT, lin_b, nullptr, f_x, nullptr, 1024, 512, 512);
    ln_kernel<<<256, 256, 0, stream>>>(f_x, o_h2, h2b, ln_g, ln_b);
    mm_kernel<0, true, false><<<gsm, 256, 0, stream>>>(h2b, decT, dec_b1, nullptr, f_x, nullptr, 1024, 512, 512);
    dec2_kernel<<<256, 256, 0, stream>>>(f_x, dec_w2, dec_b2, o_dec);
}